// Round 1
// baseline (2954.812 us; speedup 1.0000x reference)
//
#include <hip/hip_runtime.h>
#include <cstddef>

#define L_LEN 4096
#define RWID 256
#define SWID 128
#define CDIM 16
#define NLAY 30

// ---------------- batched transpose: in[b][R][C] -> out[b][C][R] ----------------
__global__ __launch_bounds__(256) void transpose_kernel(
    const float* __restrict__ in, float* __restrict__ out, int R, int C)
{
  __shared__ float tile[32][33];
  const size_t mat = (size_t)blockIdx.z * R * C;
  const float* src = in + mat;
  float* dst = out + mat;
  const int c0 = blockIdx.x * 32, r0 = blockIdx.y * 32;
  const int tx = threadIdx.x & 31, ty = threadIdx.x >> 5;
#pragma unroll
  for (int i = 0; i < 32; i += 8) {
    int r = r0 + ty + i, c = c0 + tx;
    if (r < R && c < C) tile[ty + i][tx] = src[(size_t)r * C + c];
  }
  __syncthreads();
#pragma unroll
  for (int i = 0; i < 32; i += 8) {
    int c = c0 + ty + i, r = r0 + tx;
    if (r < R && c < C) dst[(size_t)c * R + r] = tile[tx][ty + i];
  }
}

// ---------------- init: feat[c,t] = b[c] + sum_k w[c,0,k]*x[t+k-1] ----------------
__global__ __launch_bounds__(256) void init_feat_kernel(
    const float* __restrict__ x, const float* __restrict__ w,
    const float* __restrict__ b, float* __restrict__ feat)
{
  const int idx = blockIdx.x * 256 + threadIdx.x;
  const int c = idx >> 12, t = idx & (L_LEN - 1);
  float xm = (t > 0) ? x[t - 1] : 0.f;
  float x0 = x[t];
  float xp = (t < L_LEN - 1) ? x[t + 1] : 0.f;
  feat[idx] = b[c] + w[c * 3 + 0] * xm + w[c * 3 + 1] * x0 + w[c * 3 + 2] * xp;
}

// ---------------- residual: f/g dilated conv + cond + sigmoid*tanh ----------------
// tile: 32 co x 64 t, block 256, thread micro 2co x 4t for both f and g
__global__ __launch_bounds__(256) void residual_kernel(
    const float* __restrict__ feat, const float* __restrict__ cond,
    const float* __restrict__ wfT,   // [RW*3][RW], row = cin*3+k
    const float* __restrict__ wgT,
    const float* __restrict__ wcfT,  // [CD][RW]
    const float* __restrict__ wcgT,
    float* __restrict__ res, int d)
{
  __shared__ float wf_s[16][32];
  __shared__ float wg_s[16][32];
  __shared__ float x_s[16][64];
  const int t0 = blockIdx.x * 64;
  const int co0 = blockIdx.y * 32;
  const int tid = threadIdx.x;
  const int cg = tid >> 4, tg = tid & 15;

  float accf[2][4] = {{0.f,0.f,0.f,0.f},{0.f,0.f,0.f,0.f}};
  float accg[2][4] = {{0.f,0.f,0.f,0.f},{0.f,0.f,0.f,0.f}};

  const int r8 = tid >> 5, c32 = tid & 31;
  const int r4 = tid >> 6, c64 = tid & 63;

  for (int k = 0; k < 3; ++k) {
    const int off = (k - 1) * d;
    for (int c0 = 0; c0 < RWID; c0 += 16) {
      __syncthreads();
#pragma unroll
      for (int it = 0; it < 2; ++it) {
        int ci = c0 + r8 + it * 8;
        size_t wrow = ((size_t)ci * 3 + k) * RWID + co0 + c32;
        wf_s[r8 + it * 8][c32] = wfT[wrow];
        wg_s[r8 + it * 8][c32] = wgT[wrow];
      }
#pragma unroll
      for (int it = 0; it < 4; ++it) {
        int t = t0 + c64 + off;
        x_s[r4 + it * 4][c64] = (t >= 0 && t < L_LEN)
            ? feat[(size_t)(c0 + r4 + it * 4) * L_LEN + t] : 0.f;
      }
      __syncthreads();
#pragma unroll
      for (int ci = 0; ci < 16; ++ci) {
        const float4 xv = *(const float4*)&x_s[ci][tg * 4];
        const float2 wfv = *(const float2*)&wf_s[ci][cg * 2];
        const float2 wgv = *(const float2*)&wg_s[ci][cg * 2];
        const float xa[4] = {xv.x, xv.y, xv.z, xv.w};
        const float wfa[2] = {wfv.x, wfv.y};
        const float wga[2] = {wgv.x, wgv.y};
#pragma unroll
        for (int a = 0; a < 2; ++a)
#pragma unroll
          for (int b = 0; b < 4; ++b) {
            accf[a][b] = fmaf(wfa[a], xa[b], accf[a][b]);
            accg[a][b] = fmaf(wga[a], xa[b], accg[a][b]);
          }
      }
    }
  }

  // conditioning contribution (K = 16)
  __syncthreads();
#pragma unroll
  for (int it = 0; it < 2; ++it) {
    int j = r8 + it * 8;
    wf_s[j][c32] = wcfT[(size_t)j * RWID + co0 + c32];
    wg_s[j][c32] = wcgT[(size_t)j * RWID + co0 + c32];
  }
#pragma unroll
  for (int it = 0; it < 4; ++it)
    x_s[r4 + it * 4][c64] = cond[(size_t)(r4 + it * 4) * L_LEN + t0 + c64];
  __syncthreads();
#pragma unroll
  for (int ci = 0; ci < 16; ++ci) {
    const float4 xv = *(const float4*)&x_s[ci][tg * 4];
    const float2 wfv = *(const float2*)&wf_s[ci][cg * 2];
    const float2 wgv = *(const float2*)&wg_s[ci][cg * 2];
    const float xa[4] = {xv.x, xv.y, xv.z, xv.w};
    const float wfa[2] = {wfv.x, wfv.y};
    const float wga[2] = {wgv.x, wgv.y};
#pragma unroll
    for (int a = 0; a < 2; ++a)
#pragma unroll
      for (int b = 0; b < 4; ++b) {
        accf[a][b] = fmaf(wfa[a], xa[b], accf[a][b]);
        accg[a][b] = fmaf(wga[a], xa[b], accg[a][b]);
      }
  }

  // nonlinearity + store
#pragma unroll
  for (int a = 0; a < 2; ++a) {
    float o[4];
#pragma unroll
    for (int b = 0; b < 4; ++b) {
      float f = accf[a][b], g = accg[a][b];
      float sig = 1.f / (1.f + __expf(-f));
      float ag = fabsf(g);
      float th = 1.f - 2.f / (__expf(2.f * ag) + 1.f);
      th = (g < 0.f) ? -th : th;
      o[b] = sig * th;
    }
    *(float4*)&res[(size_t)(co0 + cg * 2 + a) * L_LEN + t0 + tg * 4] = *(float4*)o;
  }
}

// ---------------- update: feat += WfeatT^T @ res ; skip += WskipT^T @ res ----------
__global__ __launch_bounds__(256) void update_kernel(
    const float* __restrict__ res,
    const float* __restrict__ wfeatT,  // [256][256]
    const float* __restrict__ wskipT,  // [256][128]
    float* __restrict__ feat, float* __restrict__ skip)
{
  __shared__ float w_s[16][32];
  __shared__ float x_s[16][64];
  const int t0 = blockIdx.x * 64;
  const bool isSkip = blockIdx.y >= 8;
  const int m0 = (isSkip ? ((int)blockIdx.y - 8) : (int)blockIdx.y) * 32;
  const float* WT = isSkip ? wskipT : wfeatT;
  const int M = isSkip ? SWID : RWID;
  float* dst = isSkip ? skip : feat;
  const int tid = threadIdx.x;
  const int cg = tid >> 4, tg = tid & 15;
  const int r8 = tid >> 5, c32 = tid & 31;
  const int r4 = tid >> 6, c64 = tid & 63;

  float acc[2][4] = {{0.f,0.f,0.f,0.f},{0.f,0.f,0.f,0.f}};

  for (int k0 = 0; k0 < RWID; k0 += 16) {
    __syncthreads();
#pragma unroll
    for (int it = 0; it < 2; ++it)
      w_s[r8 + it * 8][c32] = WT[(size_t)(k0 + r8 + it * 8) * M + m0 + c32];
#pragma unroll
    for (int it = 0; it < 4; ++it)
      x_s[r4 + it * 4][c64] = res[(size_t)(k0 + r4 + it * 4) * L_LEN + t0 + c64];
    __syncthreads();
#pragma unroll
    for (int ci = 0; ci < 16; ++ci) {
      const float4 xv = *(const float4*)&x_s[ci][tg * 4];
      const float2 wv = *(const float2*)&w_s[ci][cg * 2];
      const float xa[4] = {xv.x, xv.y, xv.z, xv.w};
      const float wa[2] = {wv.x, wv.y};
#pragma unroll
      for (int a = 0; a < 2; ++a)
#pragma unroll
        for (int b = 0; b < 4; ++b)
          acc[a][b] = fmaf(wa[a], xa[b], acc[a][b]);
    }
  }
#pragma unroll
  for (int a = 0; a < 2; ++a) {
    float4* p = (float4*)&dst[(size_t)(m0 + cg * 2 + a) * L_LEN + t0 + tg * 4];
    float4 old = *p;
    old.x += acc[a][0]; old.y += acc[a][1]; old.z += acc[a][2]; old.w += acc[a][3];
    *p = old;
  }
}

// ---------------- generic gemm: C[m][t] = (bias) + sum_k WT[k][m]*op(X[k][t]) -------
template<bool RELU, bool BIAS>
__global__ __launch_bounds__(256) void gemm_kernel(
    const float* __restrict__ WT, const float* __restrict__ X,
    const float* __restrict__ bias, float* __restrict__ C, int M, int Ktot)
{
  __shared__ float w_s[16][32];
  __shared__ float x_s[16][64];
  const int t0 = blockIdx.x * 64;
  const int m0 = blockIdx.y * 32;
  const int tid = threadIdx.x;
  const int cg = tid >> 4, tg = tid & 15;
  const int r8 = tid >> 5, c32 = tid & 31;
  const int r4 = tid >> 6, c64 = tid & 63;

  float acc[2][4] = {{0.f,0.f,0.f,0.f},{0.f,0.f,0.f,0.f}};

  for (int k0 = 0; k0 < Ktot; k0 += 16) {
    __syncthreads();
#pragma unroll
    for (int it = 0; it < 2; ++it)
      w_s[r8 + it * 8][c32] = WT[(size_t)(k0 + r8 + it * 8) * M + m0 + c32];
#pragma unroll
    for (int it = 0; it < 4; ++it) {
      float v = X[(size_t)(k0 + r4 + it * 4) * L_LEN + t0 + c64];
      if (RELU) v = fmaxf(v, 0.f);
      x_s[r4 + it * 4][c64] = v;
    }
    __syncthreads();
#pragma unroll
    for (int ci = 0; ci < 16; ++ci) {
      const float4 xv = *(const float4*)&x_s[ci][tg * 4];
      const float2 wv = *(const float2*)&w_s[ci][cg * 2];
      const float xa[4] = {xv.x, xv.y, xv.z, xv.w};
      const float wa[2] = {wv.x, wv.y};
#pragma unroll
      for (int a = 0; a < 2; ++a)
#pragma unroll
        for (int b = 0; b < 4; ++b)
          acc[a][b] = fmaf(wa[a], xa[b], acc[a][b]);
    }
  }
#pragma unroll
  for (int a = 0; a < 2; ++a) {
    float bb = BIAS ? bias[m0 + cg * 2 + a] : 0.f;
    float o[4];
#pragma unroll
    for (int b = 0; b < 4; ++b) o[b] = acc[a][b] + bb;
    *(float4*)&C[(size_t)(m0 + cg * 2 + a) * L_LEN + t0 + tg * 4] = *(float4*)o;
  }
}

extern "C" void kernel_launch(void* const* d_in, const int* in_sizes, int n_in,
                              void* d_out, int out_size, void* d_ws, size_t ws_size,
                              hipStream_t stream) {
  const float* x            = (const float*)d_in[0];
  const float* cond         = (const float*)d_in[1];
  const float* init_w       = (const float*)d_in[2];
  const float* init_b       = (const float*)d_in[3];
  const float* init_skip_w  = (const float*)d_in[4];
  const float* init_skip_b  = (const float*)d_in[5];
  const float* filter_w     = (const float*)d_in[6];
  const float* gate_w       = (const float*)d_in[7];
  const float* skip_w       = (const float*)d_in[8];
  const float* feat_w       = (const float*)d_in[9];
  const float* fcond_w      = (const float*)d_in[10];
  const float* gcond_w      = (const float*)d_in[11];
  const float* final_skip_w = (const float*)d_in[12];
  const float* final_skip_b = (const float*)d_in[13];
  const float* final_w      = (const float*)d_in[14];
  const float* final_b      = (const float*)d_in[15];
  float* out = (float*)d_out;

  float* ws = (float*)d_ws;
  size_t off = 0;
  auto alloc = [&](size_t n) { float* p = ws + off; off += n; return p; };
  float* feat   = alloc((size_t)RWID * L_LEN);
  float* res    = alloc((size_t)RWID * L_LEN);
  float* skip   = alloc((size_t)SWID * L_LEN);
  float* skip2  = alloc((size_t)SWID * L_LEN);
  float* wfT    = alloc((size_t)NLAY * 768 * 256);
  float* wgT    = alloc((size_t)NLAY * 768 * 256);
  float* wcfT   = alloc((size_t)NLAY * 16 * 256);
  float* wcgT   = alloc((size_t)NLAY * 16 * 256);
  float* wfeatT = alloc((size_t)NLAY * 256 * 256);
  float* wskipT = alloc((size_t)NLAY * 256 * 128);
  float* wiskT  = alloc((size_t)256 * 128);
  float* wfskT  = alloc((size_t)128 * 128);
  float* wfinT  = alloc((size_t)128 * 256);
  (void)ws_size; (void)n_in; (void)in_sizes; (void)out_size;

  const dim3 B256(256);
  // weight transposes (must rerun every call: d_ws is re-poisoned)
  transpose_kernel<<<dim3(24, 8, NLAY), B256, 0, stream>>>(filter_w, wfT, 256, 768);
  transpose_kernel<<<dim3(24, 8, NLAY), B256, 0, stream>>>(gate_w,   wgT, 256, 768);
  transpose_kernel<<<dim3(8, 8, NLAY),  B256, 0, stream>>>(feat_w, wfeatT, 256, 256);
  transpose_kernel<<<dim3(8, 4, NLAY),  B256, 0, stream>>>(skip_w, wskipT, 128, 256);
  transpose_kernel<<<dim3(1, 8, NLAY),  B256, 0, stream>>>(fcond_w, wcfT, 256, 16);
  transpose_kernel<<<dim3(1, 8, NLAY),  B256, 0, stream>>>(gcond_w, wcgT, 256, 16);
  transpose_kernel<<<dim3(8, 4, 1),     B256, 0, stream>>>(init_skip_w, wiskT, 128, 256);
  transpose_kernel<<<dim3(4, 4, 1),     B256, 0, stream>>>(final_skip_w, wfskT, 128, 128);
  transpose_kernel<<<dim3(4, 8, 1),     B256, 0, stream>>>(final_w, wfinT, 256, 128);

  // init feature plane + skip
  init_feat_kernel<<<dim3(L_LEN), B256, 0, stream>>>(x, init_w, init_b, feat);
  gemm_kernel<false, true><<<dim3(64, 4), B256, 0, stream>>>(wiskT, feat, init_skip_b, skip, SWID, RWID);

  // 30 residual layers
  for (int i = 0; i < NLAY; ++i) {
    const int d = 1 << (i % 10);
    residual_kernel<<<dim3(64, 8), B256, 0, stream>>>(
        feat, cond,
        wfT + (size_t)i * 768 * 256, wgT + (size_t)i * 768 * 256,
        wcfT + (size_t)i * 16 * 256, wcgT + (size_t)i * 16 * 256,
        res, d);
    update_kernel<<<dim3(64, 12), B256, 0, stream>>>(
        res, wfeatT + (size_t)i * 256 * 256, wskipT + (size_t)i * 256 * 128,
        feat, skip);
  }

  // final: relu -> 1x1 -> relu -> 1x1
  gemm_kernel<true, true><<<dim3(64, 4), B256, 0, stream>>>(wfskT, skip, final_skip_b, skip2, SWID, SWID);
  gemm_kernel<true, true><<<dim3(64, 8), B256, 0, stream>>>(wfinT, skip2, final_b, out, RWID, SWID);
}

// Round 2
// 788.421 us; speedup vs baseline: 3.7478x; 3.7478x over previous
//
#include <hip/hip_runtime.h>
#include <cstddef>
#include <cstdint>

#define L_LEN 4096
#define RWID 256
#define SWID 128
#define NLAY 30

typedef __attribute__((ext_vector_type(8))) short bf16x8;
typedef __attribute__((ext_vector_type(4))) float f32x4;

__device__ __forceinline__ ushort f2bf(float x) {
  union { float f; uint32_t u; } v; v.f = x;
  uint32_t r = v.u + 0x7fffu + ((v.u >> 16) & 1u);
  return (ushort)(r >> 16);
}

__device__ __forceinline__ void gload16(const void* g, void* l) {
  __builtin_amdgcn_global_load_lds(
      (const __attribute__((address_space(1))) void*)g,
      (__attribute__((address_space(3))) void*)l, 16, 0, 0);
}

__device__ __forceinline__ f32x4 mfma16(bf16x8 a, bf16x8 b, f32x4 c) {
  return __builtin_amdgcn_mfma_f32_16x16x32_bf16(a, b, c, 0, 0, 0);
}

// ============================ weight prep ============================
// wres[i][fg][co][k], k = tap*256 + cin for k<768; 768..783 = cond; 784..799 = 0
__global__ __launch_bounds__(256) void prep_wres(
    const float* __restrict__ filter_w, const float* __restrict__ gate_w,
    const float* __restrict__ fcond_w, const float* __restrict__ gcond_w,
    ushort* __restrict__ wres)
{
  const int idx = blockIdx.x * 256 + threadIdx.x;   // < 30*2*256*800
  const int k = idx % 800;
  int rest = idx / 800;
  const int co = rest & 255; rest >>= 8;
  const int fg = rest & 1;
  const int i = rest >> 1;
  float v;
  if (k < 768) {
    const int tap = k >> 8, cin = k & 255;
    const float* s = fg ? gate_w : filter_w;
    v = s[(((size_t)i * 256 + co) * 256 + cin) * 3 + tap];
  } else if (k < 784) {
    const float* s = fg ? gcond_w : fcond_w;
    v = s[((size_t)i * 256 + co) * 16 + (k - 768)];
  } else v = 0.f;
  wres[idx] = f2bf(v);
}

// wu[i][m][rc]: m<256 -> feat_w, m>=256 -> skip_w
__global__ __launch_bounds__(256) void prep_wu(
    const float* __restrict__ feat_w, const float* __restrict__ skip_w,
    ushort* __restrict__ wu)
{
  const int idx = blockIdx.x * 256 + threadIdx.x;   // < 30*384*256
  const int rc = idx & 255;
  const int rest = idx >> 8;
  const int m = rest % 384;
  const int i = rest / 384;
  float v = (m < 256) ? feat_w[((size_t)i * 256 + m) * 256 + rc]
                      : skip_w[((size_t)i * 128 + (m - 256)) * 256 + rc];
  wu[idx] = f2bf(v);
}

// condT[4096][32] (cols>=16 zero), wisk[128][256], wfsk[128][128], wfin[256][128], zerobuf
__global__ __launch_bounds__(256) void prep_misc(
    const float* __restrict__ cond, const float* __restrict__ isw,
    const float* __restrict__ fsw, const float* __restrict__ fw,
    ushort* __restrict__ condT, ushort* __restrict__ wisk,
    ushort* __restrict__ wfsk, ushort* __restrict__ wfin,
    ushort* __restrict__ zerobuf)
{
  const int idx = blockIdx.x * 256 + threadIdx.x;
  if (idx < 131072) {
    const int t = idx >> 5, cd = idx & 31;
    condT[idx] = (cd < 16) ? f2bf(cond[(size_t)cd * L_LEN + t]) : (ushort)0;
  } else if (idx < 131072 + 32768) {
    const int j = idx - 131072; wisk[j] = f2bf(isw[j]);
  } else if (idx < 131072 + 32768 + 16384) {
    const int j = idx - (131072 + 32768); wfsk[j] = f2bf(fsw[j]);
  } else if (idx < 131072 + 32768 + 16384 + 32768) {
    const int j = idx - (131072 + 32768 + 16384); wfin[j] = f2bf(fw[j]);
  } else if (idx < 131072 + 32768 + 16384 + 32768 + 128) {
    zerobuf[idx - (131072 + 32768 + 16384 + 32768)] = 0;
  }
}

// ============================ init feature ============================
// featT[t][c] = init_b[c] + sum_k init_w[c][k] * x[t+k-1]
__global__ __launch_bounds__(256) void init_feat(
    const float* __restrict__ x, const float* __restrict__ w,
    const float* __restrict__ b, float* __restrict__ featT_f32,
    ushort* __restrict__ featT_bf16)
{
  const int t = blockIdx.x, c = threadIdx.x;
  const float xm = (t > 0) ? x[t - 1] : 0.f;
  const float x0 = x[t];
  const float xp = (t < L_LEN - 1) ? x[t + 1] : 0.f;
  const float v = b[c] + w[c * 3] * xm + w[c * 3 + 1] * x0 + w[c * 3 + 2] * xp;
  featT_f32[(size_t)t * 256 + c] = v;
  featT_bf16[(size_t)t * 256 + c] = f2bf(v);
}

// ============================ residual (f/g) MFMA ============================
// Tile 32co x 128t. K=800 in 25 chunks of 32. LDS [2 buf][Af 1024 | Ag 1024 | B 4096] ushorts.
// XOR swizzle: 16B-oct position p = oct ^ ((row>>1)&3), applied on BOTH stage-src and read.
__global__ __launch_bounds__(256) void residual_mfma(
    const ushort* __restrict__ featT,   // [4096][256] bf16
    const ushort* __restrict__ condT,   // [4096][32] bf16
    const ushort* __restrict__ wres,    // [2][256][800] bf16 (this layer)
    const ushort* __restrict__ zerobuf,
    ushort* __restrict__ resT,          // [4096][256] bf16
    int d)
{
  __shared__ ushort lds[2][6144];
  const int t0  = blockIdx.x * 128;
  const int co0 = blockIdx.y * 32;
  const int tid = threadIdx.x;
  const int lane = tid & 63;
  const int w    = tid >> 6;

  // staging lane geometry (16 rows x 64B per instruction)
  const int srow = lane >> 2;
  const int soct = (lane & 3) ^ ((srow >> 1) & 3);

  const int fgA  = w >> 1;                  // wave 0,1 -> filter; 2,3 -> gate
  const int arow = ((w & 1) << 4) + srow;   // row within 32-co tile
  const ushort* asrc0 = wres + ((size_t)fgA * 256 + (co0 + arow)) * 800 + soct * 8;
  const int aLds = fgA * 1024 + (w & 1) * 512;
  const int bLds = 2048 + w * 1024;

  // compute-side fragment offsets (ushort units, fixed per lane)
  const int rl   = lane & 15;
  const int octr = (lane >> 4) ^ ((rl >> 1) & 3);
  const int aoff = rl * 32 + octr * 8;
  const int boff = 2048 + (w * 32 + rl) * 32 + octr * 8;

  f32x4 accf[2][2] = {}; f32x4 accg[2][2] = {};

  auto stage = [&](int kc, int buf) {
    const int k0 = kc * 32;
    gload16(asrc0 + k0, &lds[buf][aLds]);
#pragma unroll
    for (int j = 0; j < 2; ++j) {
      const int rB = w * 32 + j * 16 + srow;
      const ushort* bsrc;
      if (kc < 24) {
        const int tap = kc >> 3, cin0 = (kc & 7) * 32;
        const int tt = t0 + rB + (tap - 1) * d;
        bsrc = (tt >= 0 && tt < L_LEN)
                 ? featT + (size_t)tt * 256 + cin0 + soct * 8
                 : zerobuf;
      } else {
        bsrc = condT + (size_t)(t0 + rB) * 32 + soct * 8;
      }
      gload16(bsrc, &lds[buf][bLds + j * 512]);
    }
  };

  stage(0, 0);
  __syncthreads();
  for (int kc = 0; kc < 25; ++kc) {
    const int cur = kc & 1;
    if (kc + 1 < 25) stage(kc + 1, cur ^ 1);
    const ushort* base = lds[cur];
    bf16x8 af0 = *(const bf16x8*)(base + aoff);
    bf16x8 af1 = *(const bf16x8*)(base + aoff + 512);
    bf16x8 ag0 = *(const bf16x8*)(base + aoff + 1024);
    bf16x8 ag1 = *(const bf16x8*)(base + aoff + 1536);
    bf16x8 b0  = *(const bf16x8*)(base + boff);
    bf16x8 b1  = *(const bf16x8*)(base + boff + 512);
    accf[0][0] = mfma16(af0, b0, accf[0][0]);
    accf[0][1] = mfma16(af0, b1, accf[0][1]);
    accf[1][0] = mfma16(af1, b0, accf[1][0]);
    accf[1][1] = mfma16(af1, b1, accf[1][1]);
    accg[0][0] = mfma16(ag0, b0, accg[0][0]);
    accg[0][1] = mfma16(ag0, b1, accg[0][1]);
    accg[1][0] = mfma16(ag1, b0, accg[1][0]);
    accg[1][1] = mfma16(ag1, b1, accg[1][1]);
    __syncthreads();
  }

  // epilogue: sigmoid(f)*tanh(g) -> resT[t][co] bf16 (8B per frag)
  const int cobase = co0 + (lane >> 4) * 4;
#pragma unroll
  for (int m = 0; m < 2; ++m)
#pragma unroll
    for (int n = 0; n < 2; ++n) {
      const f32x4 f = accf[m][n], g = accg[m][n];
      ushort4 ov;
      float o[4];
#pragma unroll
      for (int r = 0; r < 4; ++r) {
        const float ff = f[r], gg = g[r];
        const float sig = 1.f / (1.f + __expf(-ff));
        const float ag2 = fabsf(gg);
        float th = 1.f - 2.f / (__expf(2.f * ag2) + 1.f);
        th = (gg < 0.f) ? -th : th;
        o[r] = sig * th;
      }
      ov.x = f2bf(o[0]); ov.y = f2bf(o[1]); ov.z = f2bf(o[2]); ov.w = f2bf(o[3]);
      const int t = t0 + w * 32 + n * 16 + rl;
      *(ushort4*)&resT[(size_t)t * 256 + cobase + m * 16] = ov;
    }
}

// ============================ update MFMA ============================
// Tile 32m x 128t, K=256 (8 chunks). m<256: featT_f32 += acc (+bf16 shadow); else skipT_f32 +=.
__global__ __launch_bounds__(256) void update_mfma(
    const ushort* __restrict__ resT,   // [4096][256]
    const ushort* __restrict__ wu,     // [384][256] this layer
    float* __restrict__ featT_f32, ushort* __restrict__ featT_bf16,
    float* __restrict__ skipT_f32)
{
  __shared__ ushort lds[2][5120];
  const int t0 = blockIdx.x * 128;
  const int m0 = blockIdx.y * 32;
  const int tid = threadIdx.x;
  const int lane = tid & 63;
  const int w    = tid >> 6;

  const int srow = lane >> 2;
  const int soct = (lane & 3) ^ ((srow >> 1) & 3);

  const ushort* asrc0 = wu + (size_t)(m0 + (w & 1) * 16 + srow) * 256 + soct * 8;
  const int aLds = (w & 1) * 512;
  const int bLds = 1024 + w * 1024;

  const int rl   = lane & 15;
  const int octr = (lane >> 4) ^ ((rl >> 1) & 3);
  const int aoff = rl * 32 + octr * 8;
  const int boff = 1024 + (w * 32 + rl) * 32 + octr * 8;

  f32x4 acc[2][2] = {};

  auto stage = [&](int kc, int buf) {
    const int k0 = kc * 32;
    if (w < 2) gload16(asrc0 + k0, &lds[buf][aLds]);
#pragma unroll
    for (int j = 0; j < 2; ++j) {
      const int rB = w * 32 + j * 16 + srow;
      gload16(resT + (size_t)(t0 + rB) * 256 + k0 + soct * 8, &lds[buf][bLds + j * 512]);
    }
  };

  stage(0, 0);
  __syncthreads();
  for (int kc = 0; kc < 8; ++kc) {
    const int cur = kc & 1;
    if (kc + 1 < 8) stage(kc + 1, cur ^ 1);
    const ushort* base = lds[cur];
    bf16x8 a0 = *(const bf16x8*)(base + aoff);
    bf16x8 a1 = *(const bf16x8*)(base + aoff + 512);
    bf16x8 b0 = *(const bf16x8*)(base + boff);
    bf16x8 b1 = *(const bf16x8*)(base + boff + 512);
    acc[0][0] = mfma16(a0, b0, acc[0][0]);
    acc[0][1] = mfma16(a0, b1, acc[0][1]);
    acc[1][0] = mfma16(a1, b0, acc[1][0]);
    acc[1][1] = mfma16(a1, b1, acc[1][1]);
    __syncthreads();
  }

  const int mbase = m0 + (lane >> 4) * 4;
#pragma unroll
  for (int m = 0; m < 2; ++m)
#pragma unroll
    for (int n = 0; n < 2; ++n) {
      const int t = t0 + w * 32 + n * 16 + rl;
      const int mm = mbase + m * 16;
      const f32x4 a = acc[m][n];
      if (m0 < 256) {
        float4* p = (float4*)&featT_f32[(size_t)t * 256 + mm];
        float4 v = *p;
        v.x += a[0]; v.y += a[1]; v.z += a[2]; v.w += a[3];
        *p = v;
        ushort4 ov; ov.x = f2bf(v.x); ov.y = f2bf(v.y); ov.z = f2bf(v.z); ov.w = f2bf(v.w);
        *(ushort4*)&featT_bf16[(size_t)t * 256 + mm] = ov;
      } else {
        float4* p = (float4*)&skipT_f32[(size_t)t * 128 + (mm - 256)];
        float4 v = *p;
        v.x += a[0]; v.y += a[1]; v.z += a[2]; v.w += a[3];
        *p = v;
      }
    }
}

// ============================ generic 1x1 MFMA GEMM ============================
// MODE 0: acc+bias -> fp32 [t][128] (overwrite)   (init skip)
// MODE 1: relu(acc+bias) -> bf16 [t][128]          (skip2)
// MODE 2: acc+bias -> fp32 [m][4096]               (final out)
template<int MODE, int KLEN>
__global__ __launch_bounds__(256) void gemm_mfma(
    const ushort* __restrict__ A,    // [M][KLEN] bf16
    const ushort* __restrict__ B,    // [4096][KLEN] bf16
    const float* __restrict__ bias,  // [M]
    void* __restrict__ outp)
{
  __shared__ ushort lds[2][5120];
  const int t0 = blockIdx.x * 128;
  const int m0 = blockIdx.y * 32;
  const int tid = threadIdx.x;
  const int lane = tid & 63;
  const int w    = tid >> 6;

  const int srow = lane >> 2;
  const int soct = (lane & 3) ^ ((srow >> 1) & 3);

  const ushort* asrc0 = A + (size_t)(m0 + (w & 1) * 16 + srow) * KLEN + soct * 8;
  const int aLds = (w & 1) * 512;
  const int bLds = 1024 + w * 1024;

  const int rl   = lane & 15;
  const int octr = (lane >> 4) ^ ((rl >> 1) & 3);
  const int aoff = rl * 32 + octr * 8;
  const int boff = 1024 + (w * 32 + rl) * 32 + octr * 8;

  f32x4 acc[2][2] = {};
  constexpr int KSTEPS = KLEN / 32;

  auto stage = [&](int kc, int buf) {
    const int k0 = kc * 32;
    if (w < 2) gload16(asrc0 + k0, &lds[buf][aLds]);
#pragma unroll
    for (int j = 0; j < 2; ++j) {
      const int rB = w * 32 + j * 16 + srow;
      gload16(B + (size_t)(t0 + rB) * KLEN + k0 + soct * 8, &lds[buf][bLds + j * 512]);
    }
  };

  stage(0, 0);
  __syncthreads();
  for (int kc = 0; kc < KSTEPS; ++kc) {
    const int cur = kc & 1;
    if (kc + 1 < KSTEPS) stage(kc + 1, cur ^ 1);
    const ushort* base = lds[cur];
    bf16x8 a0 = *(const bf16x8*)(base + aoff);
    bf16x8 a1 = *(const bf16x8*)(base + aoff + 512);
    bf16x8 b0 = *(const bf16x8*)(base + boff);
    bf16x8 b1 = *(const bf16x8*)(base + boff + 512);
    acc[0][0] = mfma16(a0, b0, acc[0][0]);
    acc[0][1] = mfma16(a0, b1, acc[0][1]);
    acc[1][0] = mfma16(a1, b0, acc[1][0]);
    acc[1][1] = mfma16(a1, b1, acc[1][1]);
    __syncthreads();
  }

  const int mbase = m0 + (lane >> 4) * 4;
#pragma unroll
  for (int m = 0; m < 2; ++m)
#pragma unroll
    for (int n = 0; n < 2; ++n) {
      const int t = t0 + w * 32 + n * 16 + rl;
      const int mm = mbase + m * 16;
      const float4 bb = *(const float4*)&bias[mm];
      const f32x4 a = acc[m][n];
      float o[4] = {a[0] + bb.x, a[1] + bb.y, a[2] + bb.z, a[3] + bb.w};
      if (MODE == 0) {
        *(float4*)&((float*)outp)[(size_t)t * 128 + mm] = make_float4(o[0], o[1], o[2], o[3]);
      } else if (MODE == 1) {
        ushort4 ov;
        ov.x = f2bf(fmaxf(o[0], 0.f)); ov.y = f2bf(fmaxf(o[1], 0.f));
        ov.z = f2bf(fmaxf(o[2], 0.f)); ov.w = f2bf(fmaxf(o[3], 0.f));
        *(ushort4*)&((ushort*)outp)[(size_t)t * 128 + mm] = ov;
      } else {
        float* op = (float*)outp;
#pragma unroll
        for (int r = 0; r < 4; ++r) op[(size_t)(mm + r) * L_LEN + t] = o[r];
      }
    }
}

// relu + fp32->bf16 (float4 vectorized)
__global__ __launch_bounds__(256) void relu_cvt(
    const float* __restrict__ in, ushort* __restrict__ outv, int n4)
{
  const int i = blockIdx.x * 256 + threadIdx.x;
  if (i >= n4) return;
  const float4 v = ((const float4*)in)[i];
  ushort4 o;
  o.x = f2bf(fmaxf(v.x, 0.f)); o.y = f2bf(fmaxf(v.y, 0.f));
  o.z = f2bf(fmaxf(v.z, 0.f)); o.w = f2bf(fmaxf(v.w, 0.f));
  ((ushort4*)outv)[i] = o;
}

// ============================ launch ============================
extern "C" void kernel_launch(void* const* d_in, const int* in_sizes, int n_in,
                              void* d_out, int out_size, void* d_ws, size_t ws_size,
                              hipStream_t stream) {
  const float* x            = (const float*)d_in[0];
  const float* cond         = (const float*)d_in[1];
  const float* init_w       = (const float*)d_in[2];
  const float* init_b       = (const float*)d_in[3];
  const float* init_skip_w  = (const float*)d_in[4];
  const float* init_skip_b  = (const float*)d_in[5];
  const float* filter_w     = (const float*)d_in[6];
  const float* gate_w       = (const float*)d_in[7];
  const float* skip_w       = (const float*)d_in[8];
  const float* feat_w       = (const float*)d_in[9];
  const float* fcond_w      = (const float*)d_in[10];
  const float* gcond_w      = (const float*)d_in[11];
  const float* final_skip_w = (const float*)d_in[12];
  const float* final_skip_b = (const float*)d_in[13];
  const float* final_w      = (const float*)d_in[14];
  const float* final_b      = (const float*)d_in[15];
  float* out = (float*)d_out;
  (void)in_sizes; (void)n_in; (void)out_size; (void)ws_size;

  char* ws = (char*)d_ws;
  size_t off = 0;
  auto alloc = [&](size_t bytes) { void* p = ws + off; off = (off + bytes + 255) & ~(size_t)255; return p; };
  float*  featT_f32  = (float*) alloc((size_t)L_LEN * 256 * 4);
  ushort* featT_bf16 = (ushort*)alloc((size_t)L_LEN * 256 * 2);
  ushort* resT       = (ushort*)alloc((size_t)L_LEN * 256 * 2);
  float*  skipT_f32  = (float*) alloc((size_t)L_LEN * 128 * 4);
  ushort* skipR      = (ushort*)alloc((size_t)L_LEN * 128 * 2);
  ushort* skip2R     = (ushort*)alloc((size_t)L_LEN * 128 * 2);
  ushort* condT      = (ushort*)alloc((size_t)L_LEN * 32 * 2);
  ushort* wres       = (ushort*)alloc((size_t)NLAY * 2 * 256 * 800 * 2);
  ushort* wu         = (ushort*)alloc((size_t)NLAY * 384 * 256 * 2);
  ushort* wisk       = (ushort*)alloc((size_t)128 * 256 * 2);
  ushort* wfsk       = (ushort*)alloc((size_t)128 * 128 * 2);
  ushort* wfin       = (ushort*)alloc((size_t)256 * 128 * 2);
  ushort* zerobuf    = (ushort*)alloc(256);

  const dim3 B256(256);
  prep_wres<<<48000, B256, 0, stream>>>(filter_w, gate_w, fcond_w, gcond_w, wres);
  prep_wu<<<11520, B256, 0, stream>>>(feat_w, skip_w, wu);
  prep_misc<<<833, B256, 0, stream>>>(cond, init_skip_w, final_skip_w, final_w,
                                      condT, wisk, wfsk, wfin, zerobuf);
  init_feat<<<L_LEN, B256, 0, stream>>>(x, init_w, init_b, featT_f32, featT_bf16);
  gemm_mfma<0, 256><<<dim3(32, 4), B256, 0, stream>>>(wisk, featT_bf16, init_skip_b, skipT_f32);

  for (int i = 0; i < NLAY; ++i) {
    const int d = 1 << (i % 10);
    residual_mfma<<<dim3(32, 8), B256, 0, stream>>>(
        featT_bf16, condT, wres + (size_t)i * 2 * 256 * 800, zerobuf, resT, d);
    update_mfma<<<dim3(32, 12), B256, 0, stream>>>(
        resT, wu + (size_t)i * 384 * 256, featT_f32, featT_bf16, skipT_f32);
  }

  relu_cvt<<<512, B256, 0, stream>>>(skipT_f32, skipR, (L_LEN * 128) / 4);
  gemm_mfma<1, 128><<<dim3(32, 4), B256, 0, stream>>>(wfsk, skipR, final_skip_b, skip2R);
  gemm_mfma<2, 128><<<dim3(32, 8), B256, 0, stream>>>(wfin, skip2R, final_b, out);
}

// Round 3
// 722.787 us; speedup vs baseline: 4.0881x; 1.0908x over previous
//
#include <hip/hip_runtime.h>
#include <cstddef>
#include <cstdint>

#define L_LEN 4096
#define RWID 256
#define SWID 128
#define NLAY 30

typedef __attribute__((ext_vector_type(8))) short bf16x8;
typedef __attribute__((ext_vector_type(4))) float f32x4;

__device__ __forceinline__ ushort f2bf(float x) {
  union { float f; uint32_t u; } v; v.f = x;
  uint32_t r = v.u + 0x7fffu + ((v.u >> 16) & 1u);
  return (ushort)(r >> 16);
}

__device__ __forceinline__ void gload16(const void* g, void* l) {
  __builtin_amdgcn_global_load_lds(
      (const __attribute__((address_space(1))) void*)g,
      (__attribute__((address_space(3))) void*)l, 16, 0, 0);
}

__device__ __forceinline__ f32x4 mfma16(bf16x8 a, bf16x8 b, f32x4 c) {
  return __builtin_amdgcn_mfma_f32_16x16x32_bf16(a, b, c, 0, 0, 0);
}

// ============================ weight prep ============================
// wres[i][fg][co][k], k = tap*256 + cin for k<768; 768..783 = cond; 784..799 = 0
__global__ __launch_bounds__(256) void prep_wres(
    const float* __restrict__ filter_w, const float* __restrict__ gate_w,
    const float* __restrict__ fcond_w, const float* __restrict__ gcond_w,
    ushort* __restrict__ wres)
{
  const int idx = blockIdx.x * 256 + threadIdx.x;   // < 30*2*256*800
  const int k = idx % 800;
  int rest = idx / 800;
  const int co = rest & 255; rest >>= 8;
  const int fg = rest & 1;
  const int i = rest >> 1;
  float v;
  if (k < 768) {
    const int tap = k >> 8, cin = k & 255;
    const float* s = fg ? gate_w : filter_w;
    v = s[(((size_t)i * 256 + co) * 256 + cin) * 3 + tap];
  } else if (k < 784) {
    const float* s = fg ? gcond_w : fcond_w;
    v = s[((size_t)i * 256 + co) * 16 + (k - 768)];
  } else v = 0.f;
  wres[idx] = f2bf(v);
}

// wu[i][m][rc]: m<256 -> feat_w, m>=256 -> skip_w
__global__ __launch_bounds__(256) void prep_wu(
    const float* __restrict__ feat_w, const float* __restrict__ skip_w,
    ushort* __restrict__ wu)
{
  const int idx = blockIdx.x * 256 + threadIdx.x;   // < 30*384*256
  const int rc = idx & 255;
  const int rest = idx >> 8;
  const int m = rest % 384;
  const int i = rest / 384;
  float v = (m < 256) ? feat_w[((size_t)i * 256 + m) * 256 + rc]
                      : skip_w[((size_t)i * 128 + (m - 256)) * 256 + rc];
  wu[idx] = f2bf(v);
}

// condT[4096][32] (cols>=16 zero), wisk[128][256], wfsk[128][128], wfin[256][128], zerobuf
__global__ __launch_bounds__(256) void prep_misc(
    const float* __restrict__ cond, const float* __restrict__ isw,
    const float* __restrict__ fsw, const float* __restrict__ fw,
    ushort* __restrict__ condT, ushort* __restrict__ wisk,
    ushort* __restrict__ wfsk, ushort* __restrict__ wfin,
    ushort* __restrict__ zerobuf)
{
  const int idx = blockIdx.x * 256 + threadIdx.x;
  if (idx < 131072) {
    const int t = idx >> 5, cd = idx & 31;
    condT[idx] = (cd < 16) ? f2bf(cond[(size_t)cd * L_LEN + t]) : (ushort)0;
  } else if (idx < 131072 + 32768) {
    const int j = idx - 131072; wisk[j] = f2bf(isw[j]);
  } else if (idx < 131072 + 32768 + 16384) {
    const int j = idx - (131072 + 32768); wfsk[j] = f2bf(fsw[j]);
  } else if (idx < 131072 + 32768 + 16384 + 32768) {
    const int j = idx - (131072 + 32768 + 16384); wfin[j] = f2bf(fw[j]);
  } else if (idx < 131072 + 32768 + 16384 + 32768 + 512) {
    zerobuf[idx - (131072 + 32768 + 16384 + 32768)] = 0;
  }
}

// ============================ init feature ============================
__global__ __launch_bounds__(256) void init_feat(
    const float* __restrict__ x, const float* __restrict__ w,
    const float* __restrict__ b, float* __restrict__ featT_f32,
    ushort* __restrict__ featT_bf16)
{
  const int t = blockIdx.x, c = threadIdx.x;
  const float xm = (t > 0) ? x[t - 1] : 0.f;
  const float x0 = x[t];
  const float xp = (t < L_LEN - 1) ? x[t + 1] : 0.f;
  const float v = b[c] + w[c * 3] * xm + w[c * 3 + 1] * x0 + w[c * 3 + 2] * xp;
  featT_f32[(size_t)t * 256 + c] = v;
  featT_bf16[(size_t)t * 256 + c] = f2bf(v);
}

// ============================ residual (f/g) MFMA ============================
// Tile 32co x 64t, grid (64,8)=512 blocks (2/CU). 4 waves; wave owns 16 t.
// LDS/buf: Af[32][32] | Ag[32][32] | B[64][32] = 4096 ushorts. XOR oct swizzle both sides.
__global__ __launch_bounds__(256) void residual_mfma(
    const ushort* __restrict__ featT,   // [4096][256] bf16
    const ushort* __restrict__ condT,   // [4096][32] bf16
    const ushort* __restrict__ wres,    // [2][256][800] bf16 (this layer)
    const ushort* __restrict__ zerobuf,
    ushort* __restrict__ resT,          // [4096][256] bf16
    int d)
{
  __shared__ ushort lds[2][4096];
  const int t0  = blockIdx.x * 64;
  const int co0 = blockIdx.y * 32;
  const int tid = threadIdx.x;
  const int lane = tid & 63;
  const int w    = tid >> 6;

  const int srow = lane >> 2;
  const int soct = (lane & 3) ^ ((srow >> 1) & 3);

  const int fgA  = w >> 1;                  // waves 0,1 -> filter A; 2,3 -> gate A
  const int arow = ((w & 1) << 4) + srow;
  const ushort* asrc0 = wres + ((size_t)fgA * 256 + (co0 + arow)) * 800 + soct * 8;
  const int aLds = fgA * 1024 + (w & 1) * 512;
  const int bLds = 2048 + w * 512;

  const int rl   = lane & 15;
  const int octr = (lane >> 4) ^ ((rl >> 1) & 3);
  const int aoff = rl * 32 + octr * 8;
  const int boff = 2048 + (w * 16 + rl) * 32 + octr * 8;

  f32x4 accf[2] = {}; f32x4 accg[2] = {};

  auto stage = [&](int kc, int buf) {
    const int k0 = kc * 32;
    gload16(asrc0 + k0, &lds[buf][aLds]);
    const int rB = w * 16 + srow;
    const ushort* bsrc;
    if (kc < 24) {
      const int tap = kc >> 3, cin0 = (kc & 7) * 32;
      const int tt = t0 + rB + (tap - 1) * d;
      bsrc = (tt >= 0 && tt < L_LEN)
               ? featT + (size_t)tt * 256 + cin0 + soct * 8
               : zerobuf;
    } else {
      bsrc = condT + (size_t)(t0 + rB) * 32 + soct * 8;
    }
    gload16(bsrc, &lds[buf][bLds]);
  };

  stage(0, 0);
  __syncthreads();
  for (int kc = 0; kc < 25; ++kc) {
    const int cur = kc & 1;
    if (kc + 1 < 25) stage(kc + 1, cur ^ 1);
    const ushort* base = lds[cur];
    bf16x8 af0 = *(const bf16x8*)(base + aoff);
    bf16x8 af1 = *(const bf16x8*)(base + aoff + 512);
    bf16x8 ag0 = *(const bf16x8*)(base + aoff + 1024);
    bf16x8 ag1 = *(const bf16x8*)(base + aoff + 1536);
    bf16x8 b0  = *(const bf16x8*)(base + boff);
    accf[0] = mfma16(af0, b0, accf[0]);
    accf[1] = mfma16(af1, b0, accf[1]);
    accg[0] = mfma16(ag0, b0, accg[0]);
    accg[1] = mfma16(ag1, b0, accg[1]);
    __syncthreads();
  }

  const int cobase = co0 + (lane >> 4) * 4;
  const int t = t0 + w * 16 + rl;
#pragma unroll
  for (int m = 0; m < 2; ++m) {
    const f32x4 f = accf[m], g = accg[m];
    ushort4 ov;
    float o[4];
#pragma unroll
    for (int r = 0; r < 4; ++r) {
      const float ff = f[r], gg = g[r];
      const float sig = 1.f / (1.f + __expf(-ff));
      const float ag2 = fabsf(gg);
      float th = 1.f - 2.f / (__expf(2.f * ag2) + 1.f);
      th = (gg < 0.f) ? -th : th;
      o[r] = sig * th;
    }
    ov.x = f2bf(o[0]); ov.y = f2bf(o[1]); ov.z = f2bf(o[2]); ov.w = f2bf(o[3]);
    *(ushort4*)&resT[(size_t)t * 256 + cobase + m * 16] = ov;
  }
}

// ============================ update MFMA ============================
// Tile 32m x 64t, grid (64,12)=768 blocks (3/CU). K=256 (8 chunks).
__global__ __launch_bounds__(256) void update_mfma(
    const ushort* __restrict__ resT,   // [4096][256]
    const ushort* __restrict__ wu,     // [384][256] this layer
    float* __restrict__ featT_f32, ushort* __restrict__ featT_bf16,
    float* __restrict__ skipT_f32)
{
  __shared__ ushort lds[2][3072];
  const int t0 = blockIdx.x * 64;
  const int m0 = blockIdx.y * 32;
  const int tid = threadIdx.x;
  const int lane = tid & 63;
  const int w    = tid >> 6;

  const int srow = lane >> 2;
  const int soct = (lane & 3) ^ ((srow >> 1) & 3);

  const ushort* asrc0 = wu + (size_t)(m0 + (w & 1) * 16 + srow) * 256 + soct * 8;
  const int aLds = (w & 1) * 512;
  const int bLds = 1024 + w * 512;

  const int rl   = lane & 15;
  const int octr = (lane >> 4) ^ ((rl >> 1) & 3);
  const int aoff = rl * 32 + octr * 8;
  const int boff = 1024 + (w * 16 + rl) * 32 + octr * 8;

  f32x4 acc[2] = {};

  auto stage = [&](int kc, int buf) {
    const int k0 = kc * 32;
    if (w < 2) gload16(asrc0 + k0, &lds[buf][aLds]);
    const int rB = w * 16 + srow;
    gload16(resT + (size_t)(t0 + rB) * 256 + k0 + soct * 8, &lds[buf][bLds]);
  };

  stage(0, 0);
  __syncthreads();
  for (int kc = 0; kc < 8; ++kc) {
    const int cur = kc & 1;
    if (kc + 1 < 8) stage(kc + 1, cur ^ 1);
    const ushort* base = lds[cur];
    bf16x8 a0 = *(const bf16x8*)(base + aoff);
    bf16x8 a1 = *(const bf16x8*)(base + aoff + 512);
    bf16x8 b0 = *(const bf16x8*)(base + boff);
    acc[0] = mfma16(a0, b0, acc[0]);
    acc[1] = mfma16(a1, b0, acc[1]);
    __syncthreads();
  }

  const int mbase = m0 + (lane >> 4) * 4;
  const int t = t0 + w * 16 + rl;
#pragma unroll
  for (int m = 0; m < 2; ++m) {
    const int mm = mbase + m * 16;
    const f32x4 a = acc[m];
    if (m0 < 256) {
      float4* p = (float4*)&featT_f32[(size_t)t * 256 + mm];
      float4 v = *p;
      v.x += a[0]; v.y += a[1]; v.z += a[2]; v.w += a[3];
      *p = v;
      ushort4 ov; ov.x = f2bf(v.x); ov.y = f2bf(v.y); ov.z = f2bf(v.z); ov.w = f2bf(v.w);
      *(ushort4*)&featT_bf16[(size_t)t * 256 + mm] = ov;
    } else {
      float4* p = (float4*)&skipT_f32[(size_t)t * 128 + (mm - 256)];
      float4 v = *p;
      v.x += a[0]; v.y += a[1]; v.z += a[2]; v.w += a[3];
      *p = v;
    }
  }
}

// ============================ generic 1x1 MFMA GEMM ============================
// MODE 0: acc+bias -> fp32 [t][128] overwrite (init skip)
// MODE 1: relu(acc+bias) -> bf16 [t][128] (skip2)
// MODE 2: acc+bias -> fp32 [m][4096] (final out)
template<int MODE, int KLEN>
__global__ __launch_bounds__(256) void gemm_mfma(
    const ushort* __restrict__ A,    // [M][KLEN] bf16
    const ushort* __restrict__ B,    // [4096][KLEN] bf16
    const float* __restrict__ bias,  // [M]
    void* __restrict__ outp)
{
  __shared__ ushort lds[2][3072];
  const int t0 = blockIdx.x * 64;
  const int m0 = blockIdx.y * 32;
  const int tid = threadIdx.x;
  const int lane = tid & 63;
  const int w    = tid >> 6;

  const int srow = lane >> 2;
  const int soct = (lane & 3) ^ ((srow >> 1) & 3);

  const ushort* asrc0 = A + (size_t)(m0 + (w & 1) * 16 + srow) * KLEN + soct * 8;
  const int aLds = (w & 1) * 512;
  const int bLds = 1024 + w * 512;

  const int rl   = lane & 15;
  const int octr = (lane >> 4) ^ ((rl >> 1) & 3);
  const int aoff = rl * 32 + octr * 8;
  const int boff = 1024 + (w * 16 + rl) * 32 + octr * 8;

  f32x4 acc[2] = {};
  constexpr int KSTEPS = KLEN / 32;

  auto stage = [&](int kc, int buf) {
    const int k0 = kc * 32;
    if (w < 2) gload16(asrc0 + k0, &lds[buf][aLds]);
    const int rB = w * 16 + srow;
    gload16(B + (size_t)(t0 + rB) * KLEN + k0 + soct * 8, &lds[buf][bLds]);
  };

  stage(0, 0);
  __syncthreads();
  for (int kc = 0; kc < KSTEPS; ++kc) {
    const int cur = kc & 1;
    if (kc + 1 < KSTEPS) stage(kc + 1, cur ^ 1);
    const ushort* base = lds[cur];
    bf16x8 a0 = *(const bf16x8*)(base + aoff);
    bf16x8 a1 = *(const bf16x8*)(base + aoff + 512);
    bf16x8 b0 = *(const bf16x8*)(base + boff);
    acc[0] = mfma16(a0, b0, acc[0]);
    acc[1] = mfma16(a1, b0, acc[1]);
    __syncthreads();
  }

  const int mbase = m0 + (lane >> 4) * 4;
  const int t = t0 + w * 16 + rl;
#pragma unroll
  for (int m = 0; m < 2; ++m) {
    const int mm = mbase + m * 16;
    const float4 bb = *(const float4*)&bias[mm];
    const f32x4 a = acc[m];
    float o[4] = {a[0] + bb.x, a[1] + bb.y, a[2] + bb.z, a[3] + bb.w};
    if (MODE == 0) {
      *(float4*)&((float*)outp)[(size_t)t * 128 + mm] = make_float4(o[0], o[1], o[2], o[3]);
    } else if (MODE == 1) {
      ushort4 ov;
      ov.x = f2bf(fmaxf(o[0], 0.f)); ov.y = f2bf(fmaxf(o[1], 0.f));
      ov.z = f2bf(fmaxf(o[2], 0.f)); ov.w = f2bf(fmaxf(o[3], 0.f));
      *(ushort4*)&((ushort*)outp)[(size_t)t * 128 + mm] = ov;
    } else {
      float* op = (float*)outp;
#pragma unroll
      for (int r = 0; r < 4; ++r) op[(size_t)(mm + r) * L_LEN + t] = o[r];
    }
  }
}

// relu + fp32->bf16 (float4 vectorized)
__global__ __launch_bounds__(256) void relu_cvt(
    const float* __restrict__ in, ushort* __restrict__ outv, int n4)
{
  const int i = blockIdx.x * 256 + threadIdx.x;
  if (i >= n4) return;
  const float4 v = ((const float4*)in)[i];
  ushort4 o;
  o.x = f2bf(fmaxf(v.x, 0.f)); o.y = f2bf(fmaxf(v.y, 0.f));
  o.z = f2bf(fmaxf(v.z, 0.f)); o.w = f2bf(fmaxf(v.w, 0.f));
  ((ushort4*)outv)[i] = o;
}

// ============================ launch ============================
extern "C" void kernel_launch(void* const* d_in, const int* in_sizes, int n_in,
                              void* d_out, int out_size, void* d_ws, size_t ws_size,
                              hipStream_t stream) {
  const float* x            = (const float*)d_in[0];
  const float* cond         = (const float*)d_in[1];
  const float* init_w       = (const float*)d_in[2];
  const float* init_b       = (const float*)d_in[3];
  const float* init_skip_w  = (const float*)d_in[4];
  const float* init_skip_b  = (const float*)d_in[5];
  const float* filter_w     = (const float*)d_in[6];
  const float* gate_w       = (const float*)d_in[7];
  const float* skip_w       = (const float*)d_in[8];
  const float* feat_w       = (const float*)d_in[9];
  const float* fcond_w      = (const float*)d_in[10];
  const float* gcond_w      = (const float*)d_in[11];
  const float* final_skip_w = (const float*)d_in[12];
  const float* final_skip_b = (const float*)d_in[13];
  const float* final_w      = (const float*)d_in[14];
  const float* final_b      = (const float*)d_in[15];
  float* out = (float*)d_out;
  (void)in_sizes; (void)n_in; (void)out_size; (void)ws_size;

  char* ws = (char*)d_ws;
  size_t off = 0;
  auto alloc = [&](size_t bytes) { void* p = ws + off; off = (off + bytes + 255) & ~(size_t)255; return p; };
  float*  featT_f32  = (float*) alloc((size_t)L_LEN * 256 * 4);
  ushort* featT_bf16 = (ushort*)alloc((size_t)L_LEN * 256 * 2);
  ushort* resT       = (ushort*)alloc((size_t)L_LEN * 256 * 2);
  float*  skipT_f32  = (float*) alloc((size_t)L_LEN * 128 * 4);
  ushort* skipR      = (ushort*)alloc((size_t)L_LEN * 128 * 2);
  ushort* skip2R     = (ushort*)alloc((size_t)L_LEN * 128 * 2);
  ushort* condT      = (ushort*)alloc((size_t)L_LEN * 32 * 2);
  ushort* wres       = (ushort*)alloc((size_t)NLAY * 2 * 256 * 800 * 2);
  ushort* wu         = (ushort*)alloc((size_t)NLAY * 384 * 256 * 2);
  ushort* wisk       = (ushort*)alloc((size_t)128 * 256 * 2);
  ushort* wfsk       = (ushort*)alloc((size_t)128 * 128 * 2);
  ushort* wfin       = (ushort*)alloc((size_t)256 * 128 * 2);
  ushort* zerobuf    = (ushort*)alloc(1024);

  const dim3 B256(256);
  prep_wres<<<48000, B256, 0, stream>>>(filter_w, gate_w, fcond_w, gcond_w, wres);
  prep_wu<<<11520, B256, 0, stream>>>(feat_w, skip_w, wu);
  prep_misc<<<833, B256, 0, stream>>>(cond, init_skip_w, final_skip_w, final_w,
                                      condT, wisk, wfsk, wfin, zerobuf);
  init_feat<<<L_LEN, B256, 0, stream>>>(x, init_w, init_b, featT_f32, featT_bf16);
  gemm_mfma<0, 256><<<dim3(64, 4), B256, 0, stream>>>(wisk, featT_bf16, init_skip_b, skipT_f32);

  for (int i = 0; i < NLAY; ++i) {
    const int d = 1 << (i % 10);
    residual_mfma<<<dim3(64, 8), B256, 0, stream>>>(
        featT_bf16, condT, wres + (size_t)i * 2 * 256 * 800, zerobuf, resT, d);
    update_mfma<<<dim3(64, 12), B256, 0, stream>>>(
        resT, wu + (size_t)i * 384 * 256, featT_f32, featT_bf16, skipT_f32);
  }

  relu_cvt<<<512, B256, 0, stream>>>(skipT_f32, skipR, (L_LEN * 128) / 4);
  gemm_mfma<1, 128><<<dim3(64, 4), B256, 0, stream>>>(wfsk, skipR, final_skip_b, skip2R);
  gemm_mfma<2, 128><<<dim3(64, 8), B256, 0, stream>>>(wfin, skip2R, final_b, out);
}